// Round 8
// baseline (242.298 us; speedup 1.0000x reference)
//
#include <hip/hip_runtime.h>
#include <hip/hip_bf16.h>
#include <cstdint>

#define NB   128
#define CD   64
#define LD   4096
#define KC   100
#define KT   7            // 7 k-tiles of 16 -> 112 padded clusters
#define KR   (KT * 16)    // 112
#define LSPLIT 8
#define LCH  (LD / LSPLIT) // 512 l's per block
#define ITERS (LCH / 64)   // 8 inner iters of 64 l

typedef __attribute__((ext_vector_type(8))) short bf16x8;
typedef __attribute__((ext_vector_type(4))) float f32x4;
typedef __attribute__((ext_vector_type(4))) _Float16 f16x4;

__device__ __forceinline__ short bfbits(float f) {
    __hip_bfloat16 h = __float2bfloat16(f);
    return *reinterpret_cast<short*>(&h);
}
__device__ __forceinline__ float bffloat(short s) {
    __hip_bfloat16 h = *reinterpret_cast<__hip_bfloat16*>(&s);
    return __bfloat162float(h);
}

// Precompute W fragments (bf16 hi/lo, zero-padded rows) + padded bias.
// wfrag[((t*2+h)*2+s)*64 + lane] = 8 bf16: W[t*16 + (lane&15)][h*32 + (lane>>4)*8 + 0..7]
// (same data as before; now consumed as the MFMA *B* operand — A/B share the mapping)
__global__ void k_prep(const float* __restrict__ w, const float* __restrict__ b,
                       uint4* __restrict__ wfrag, float* __restrict__ b_pad)
{
    const int tid = threadIdx.x;
    if (tid < 128) b_pad[tid] = (tid < KC) ? b[tid] : -1e30f;
    if (tid < 64) {
        const int r16 = tid & 15, gg = tid >> 4;
        for (int t = 0; t < KT; ++t) {
            const int k = t * 16 + r16;
            for (int h = 0; h < 2; ++h) {
                short hi8[8], lo8[8];
                for (int j = 0; j < 8; ++j) {
                    const int c = h * 32 + gg * 8 + j;
                    float v = (k < KC) ? w[k * CD + c] : 0.f;
                    short hb = bfbits(v);
                    hi8[j] = hb;
                    lo8[j] = bfbits(v - bffloat(hb));
                }
                wfrag[((t * 2 + h) * 2 + 0) * 64 + tid] = *reinterpret_cast<uint4*>(hi8);
                wfrag[((t * 2 + h) * 2 + 1) * 64 + tid] = *reinterpret_cast<uint4*>(lo8);
            }
        }
    }
}

// Fused, BARRIER-FREE main loop. Transposed logits D-layout == agg A-layout (K=16),
// so softmax output feeds agg MFMA straight from registers. Per-wave agg partials
// over the wave's own 16 l's; cross-wave reduce via LDS slices after the loop.
__global__ __launch_bounds__(256, 2) void k_fused(
    const float* __restrict__ x, const uint4* __restrict__ wfrag,
    const float* __restrict__ b_pad,
    float* __restrict__ agg_pT, float* __restrict__ asum_pT, int n0)
{
    __shared__ __align__(16) uint4 wlds[KT * 2 * 2 * 64]; // 28672 B; reused as red buf
    __shared__ float asum_sm[4][KR];                      // 1792 B

    const int tid  = threadIdx.x;
    const int lane = tid & 63;
    const int wv   = tid >> 6;
    const int lloc = lane & 15;
    const int g    = lane >> 4;

    for (int i = tid; i < KT * 2 * 2 * 64; i += 256) wlds[i] = wfrag[i];

    const int nn = blockIdx.x >> 3;
    const int ls = blockIdx.x & 7;
    const int n  = n0 + nn;
    const float* xb = x + (size_t)n * CD * LD + ls * LCH;

    // bias: lane holds logits for k = lloc + 16t
    float bv7[KT];
#pragma unroll
    for (int t = 0; t < KT; ++t) bv7[t] = b_pad[t * 16 + lloc];

    f32x4 aagg[KT][4];
#pragma unroll
    for (int t = 0; t < KT; ++t)
#pragma unroll
        for (int ct = 0; ct < 4; ++ct) aagg[t][ct] = (f32x4){0.f, 0.f, 0.f, 0.f};
    float pasum[KT];
#pragma unroll
    for (int t = 0; t < KT; ++t) pasum[t] = 0.f;

    const bf16x8* wfp = reinterpret_cast<const bf16x8*>(wlds);
    const int lw = wv * 16 + lloc;     // lane's l for the A-frag load phase

    __syncthreads();                   // wlds ready (the only barrier before epilogue)

    for (int it = 0; it < ITERS; ++it) {
        const int lb = it * 64;

        // ---- issue ALL global loads for this iteration up front ----
        float pvc[16];                 // x[l=lw][c] column (A-frag source)
#pragma unroll
        for (int j = 0; j < 8; ++j) {
            pvc[j]     = xb[(size_t)(g * 8 + j) * LD + lb + lw];
            pvc[8 + j] = xb[(size_t)(32 + g * 8 + j) * LD + lb + lw];
        }
        float4 xv4[4];                 // x[c=16ct+lloc][l = lb+wv*16+g*4 .. +3] (B-frag source)
        const float* xt = xb + lb + wv * 16 + g * 4;
#pragma unroll
        for (int ct = 0; ct < 4; ++ct)
            xv4[ct] = *reinterpret_cast<const float4*>(xt + (size_t)(ct * 16 + lloc) * LD);

        // ---- A-frags (x hi/lo bf16) + sumsq over c ----
        float ss = 0.f;
        bf16x8 xhi0, xlo0, xhi1, xlo1;
#pragma unroll
        for (int j = 0; j < 8; ++j) {
            float v0 = pvc[j];
            ss = fmaf(v0, v0, ss);
            short h0 = bfbits(v0);
            xhi0[j] = h0; xlo0[j] = bfbits(v0 - bffloat(h0));
            float v1 = pvc[8 + j];
            ss = fmaf(v1, v1, ss);
            short h1 = bfbits(v1);
            xhi1[j] = h1; xlo1[j] = bfbits(v1 - bffloat(h1));
        }
        ss += __shfl_xor(ss, 16);
        ss += __shfl_xor(ss, 32);
        const float rnl = 1.0f / fmaxf(sqrtf(ss), 1e-12f);
        float rnr[4];                  // rn for this lane's D rows l_local = g*4+r
#pragma unroll
        for (int r = 0; r < 4; ++r) rnr[r] = __shfl(rnl, g * 4 + r, 16);

        // ---- logits MFMA, TRANSPOSED: D[l][k] = mfma(A=x, B=W) ----
        f32x4 acc[KT];
#pragma unroll
        for (int t = 0; t < KT; ++t) acc[t] = (f32x4){0.f, 0.f, 0.f, 0.f};
#pragma unroll
        for (int t = 0; t < KT; ++t) {
            bf16x8 wh0 = wfp[((t * 2 + 0) * 2 + 0) * 64 + lane];
            bf16x8 wl0 = wfp[((t * 2 + 0) * 2 + 1) * 64 + lane];
            bf16x8 wh1 = wfp[((t * 2 + 1) * 2 + 0) * 64 + lane];
            bf16x8 wl1 = wfp[((t * 2 + 1) * 2 + 1) * 64 + lane];
            acc[t] = __builtin_amdgcn_mfma_f32_16x16x32_bf16(xhi0, wh0, acc[t], 0, 0, 0);
            acc[t] = __builtin_amdgcn_mfma_f32_16x16x32_bf16(xhi1, wh1, acc[t], 0, 0, 0);
            acc[t] = __builtin_amdgcn_mfma_f32_16x16x32_bf16(xlo0, wh0, acc[t], 0, 0, 0);
            acc[t] = __builtin_amdgcn_mfma_f32_16x16x32_bf16(xlo1, wh1, acc[t], 0, 0, 0);
            acc[t] = __builtin_amdgcn_mfma_f32_16x16x32_bf16(xhi0, wl0, acc[t], 0, 0, 0);
            acc[t] = __builtin_amdgcn_mfma_f32_16x16x32_bf16(xhi1, wl1, acc[t], 0, 0, 0);
        }

        // ---- softmax over k: lane holds logits[l=g*4+r][k=lloc+16t] ----
        float mr[4] = {-3.0e38f, -3.0e38f, -3.0e38f, -3.0e38f};
#pragma unroll
        for (int t = 0; t < KT; ++t) {
#pragma unroll
            for (int r = 0; r < 4; ++r) {
                acc[t][r] = fmaf(acc[t][r], rnr[r], bv7[t]);
                mr[r] = fmaxf(mr[r], acc[t][r]);
            }
        }
#pragma unroll
        for (int r = 0; r < 4; ++r) {
            mr[r] = fmaxf(mr[r], __shfl_xor(mr[r], 1));
            mr[r] = fmaxf(mr[r], __shfl_xor(mr[r], 2));
            mr[r] = fmaxf(mr[r], __shfl_xor(mr[r], 4));
            mr[r] = fmaxf(mr[r], __shfl_xor(mr[r], 8));
        }
        float sr[4] = {0.f, 0.f, 0.f, 0.f};
#pragma unroll
        for (int t = 0; t < KT; ++t) {
#pragma unroll
            for (int r = 0; r < 4; ++r) {
                float e = __expf(acc[t][r] - mr[r]);
                acc[t][r] = e;
                sr[r] += e;
            }
        }
#pragma unroll
        for (int r = 0; r < 4; ++r) {
            sr[r] += __shfl_xor(sr[r], 1);
            sr[r] += __shfl_xor(sr[r], 2);
            sr[r] += __shfl_xor(sr[r], 4);
            sr[r] += __shfl_xor(sr[r], 8);
            sr[r] = 1.0f / sr[r];
        }

        // ---- a (f32) -> f16 A-frags; asum partials from f32 a ----
        f16x4 pa[KT];
#pragma unroll
        for (int t = 0; t < KT; ++t) {
            float a0 = acc[t][0] * sr[0];
            float a1 = acc[t][1] * sr[1];
            float a2 = acc[t][2] * sr[2];
            float a3 = acc[t][3] * sr[3];
            pasum[t] += (a0 + a1) + (a2 + a3);
            pa[t][0] = (_Float16)a0; pa[t][1] = (_Float16)a1;
            pa[t][2] = (_Float16)a2; pa[t][3] = (_Float16)a3;
        }

        // ---- B-frags: x hi/lo f16 from xv4 (loaded long ago, latency hidden) ----
        f16x4 xh4[4], xl4[4];
#pragma unroll
        for (int ct = 0; ct < 4; ++ct) {
            float vv[4] = {xv4[ct].x, xv4[ct].y, xv4[ct].z, xv4[ct].w};
#pragma unroll
            for (int j = 0; j < 4; ++j) {
                _Float16 h = (_Float16)vv[j];
                xh4[ct][j] = h;
                xl4[ct][j] = (_Float16)(vv[j] - (float)h);
            }
        }

        // ---- agg MFMA (K=16, f16): aagg[t][ct] += a^T · x^T, straight from regs ----
#pragma unroll
        for (int t = 0; t < KT; ++t)
#pragma unroll
            for (int ct = 0; ct < 4; ++ct) {
                aagg[t][ct] = __builtin_amdgcn_mfma_f32_16x16x16f16(pa[t], xh4[ct], aagg[t][ct], 0, 0, 0);
                aagg[t][ct] = __builtin_amdgcn_mfma_f32_16x16x16f16(pa[t], xl4[ct], aagg[t][ct], 0, 0, 0);
            }
    }

    // ---- epilogue: asum reduce (g via shfl, waves via LDS) ----
#pragma unroll
    for (int t = 0; t < KT; ++t) {
        float v = pasum[t];
        v += __shfl_xor(v, 16);
        v += __shfl_xor(v, 32);
        if (g == 0) asum_sm[wv][t * 16 + lloc] = v;
    }
    __syncthreads();   // asum_sm ready; all waves done reading wlds

    const size_t nls = (size_t)nn * LSPLIT + ls;
    if (tid < KR)
        asum_pT[nls * KR + tid] = asum_sm[0][tid] + asum_sm[1][tid]
                                + asum_sm[2][tid] + asum_sm[3][tid];

    // ---- agg cross-wave reduce: 7 k-slices through LDS (reuse wlds) ----
    float* red = reinterpret_cast<float*>(wlds);   // [4][16][65] = 16640 B
#define RED(w, k, c) red[(((w) * 16 + (k)) * 65) + (c)]
    for (int t = 0; t < KT; ++t) {
        if (t) __syncthreads();        // prev slice fully consumed
        // D of agg: lane holds agg[k=16t+g*4+rg][c=16ct+lloc]
#pragma unroll
        for (int ct = 0; ct < 4; ++ct)
#pragma unroll
            for (int rg = 0; rg < 4; ++rg)
                RED(wv, g * 4 + rg, ct * 16 + lloc) = aagg[t][ct][rg];
        __syncthreads();
        const int kk = tid >> 4, c0 = (tid & 15) * 4;
        f32x4 v;
#pragma unroll
        for (int q = 0; q < 4; ++q)
            v[q] = RED(0, kk, c0 + q) + RED(1, kk, c0 + q)
                 + RED(2, kk, c0 + q) + RED(3, kk, c0 + q);
        *reinterpret_cast<f32x4*>(agg_pT + ((nls * 128 + t * 16 + kk) * 64 + c0)) = v;
    }
#undef RED
}

// Final: reduce partials ([nls][k128][c64] layout), subtract centroid*asum,
// intra-norm over C, global L2 norm.
__global__ __launch_bounds__(256, 1) void k_final(
    const float* __restrict__ agg_pT, const float* __restrict__ asum_pT,
    const float* __restrict__ cent, float* __restrict__ out, int n0)
{
    __shared__ float vbuf[KC][65];
    __shared__ float asum_s[KR];
    __shared__ float rn_s[KC];
    __shared__ float red[256];

    const int tid = threadIdx.x;
    const int nn  = blockIdx.x;
    const int n   = n0 + nn;
    const size_t nb8 = (size_t)nn * LSPLIT;

    if (tid < KR) {
        float s = 0.f;
#pragma unroll
        for (int ls = 0; ls < LSPLIT; ++ls)
            s += asum_pT[(nb8 + ls) * KR + tid];
        asum_s[tid] = s;
    }
    __syncthreads();

    for (int idx = tid; idx < 128 * 64; idx += 256) {
        int k = idx >> 6, c = idx & 63;
        if (k < KC) {
            float s = 0.f;
#pragma unroll
            for (int ls = 0; ls < LSPLIT; ++ls)
                s += agg_pT[((nb8 + ls) * 128 + k) * 64 + c];
            vbuf[k][c] = fmaf(-cent[k * CD + c], asum_s[k], s);
        }
    }
    __syncthreads();

    if (tid < KC) {
        float ssq = 0.f;
#pragma unroll 8
        for (int c = 0; c < CD; ++c) {
            float v = vbuf[tid][c];
            ssq = fmaf(v, v, ssq);
        }
        rn_s[tid] = 1.0f / fmaxf(sqrtf(ssq), 1e-12f);
    }
    __syncthreads();

    float gp = 0.f;
    for (int idx = tid; idx < KC * CD; idx += 256) {
        int k = idx >> 6, c = idx & 63;
        float v = vbuf[k][c] * rn_s[k];
        gp = fmaf(v, v, gp);
    }
    red[tid] = gp;
    __syncthreads();
    for (int off = 128; off > 0; off >>= 1) {
        if (tid < off) red[tid] += red[tid + off];
        __syncthreads();
    }
    const float gnorm = 1.0f / fmaxf(sqrtf(red[0]), 1e-12f);

    float* op = out + (size_t)n * (KC * CD);
    for (int idx = tid; idx < KC * CD; idx += 256) {
        int k = idx >> 6, c = idx & 63;
        op[idx] = vbuf[k][c] * rn_s[k] * gnorm;
    }
}

extern "C" void kernel_launch(void* const* d_in, const int* in_sizes, int n_in,
                              void* d_out, int out_size, void* d_ws, size_t ws_size,
                              hipStream_t stream)
{
    const float* x  = (const float*)d_in[0];
    const float* w  = (const float*)d_in[1];
    const float* b  = (const float*)d_in[2];
    const float* ct = (const float*)d_in[3];
    float* out = (float*)d_out;

    char* wsp = (char*)d_ws;
    uint4* wfrag = (uint4*)wsp;                 // 28672 B
    float* b_pad = (float*)(wsp + 28672);       // 512 B
    char* chunk  = wsp + 32768;

    const size_t agg_per_n  = (size_t)LSPLIT * 128 * 64 * 4; // 262144 B
    const size_t asum_per_n = (size_t)LSPLIT * KR * 4;       // 3584 B
    const size_t per_n = agg_per_n + asum_per_n;

    size_t avail = ws_size > 32768 ? ws_size - 32768 : 0;
    int nc = (int)(avail / per_n);
    if (nc < 1) nc = 1;
    if (nc > NB) nc = NB;

    float* agg_pT  = (float*)chunk;
    float* asum_pT = (float*)(chunk + agg_per_n * (size_t)nc);

    k_prep<<<1, 128, 0, stream>>>(w, b, wfrag, b_pad);
    for (int n0 = 0; n0 < NB; n0 += nc) {
        int cn = NB - n0; if (cn > nc) cn = nc;
        k_fused<<<cn * LSPLIT, 256, 0, stream>>>(x, wfrag, b_pad, agg_pT, asum_pT, n0);
        k_final<<<cn, 256, 0, stream>>>(agg_pT, asum_pT, ct, out, n0);
    }
}

// Round 9
// 101.841 us; speedup vs baseline: 2.3792x; 2.3792x over previous
//
#include <hip/hip_runtime.h>
#include <hip/hip_bf16.h>
#include <cstdint>

#define NB   128
#define CD   64
#define LD   4096
#define KC   100
#define KT   7            // 7 k-tiles of 16 -> 112 padded clusters
#define KR   (KT * 16)    // 112
#define LSPLIT 8
#define LCH  (LD / LSPLIT) // 512 l's per block
#define ITERS (LCH / 64)   // 8 inner iters of 64 l

typedef __attribute__((ext_vector_type(8))) short bf16x8;
typedef __attribute__((ext_vector_type(4))) float f32x4;
typedef __attribute__((ext_vector_type(4))) _Float16 f16x4;

__device__ __forceinline__ short bfbits(float f) {
    __hip_bfloat16 h = __float2bfloat16(f);
    return *reinterpret_cast<short*>(&h);
}
__device__ __forceinline__ float bffloat(short s) {
    __hip_bfloat16 h = *reinterpret_cast<__hip_bfloat16*>(&s);
    return __bfloat162float(h);
}

// Precompute W fragments (bf16 hi/lo, zero-padded rows) + padded bias.
// wfrag[((t*2+h)*2+s)*64 + lane] = 8 bf16: W[t*16 + (lane&15)][h*32 + (lane>>4)*8 + 0..7]
__global__ void k_prep(const float* __restrict__ w, const float* __restrict__ b,
                       uint4* __restrict__ wfrag, float* __restrict__ b_pad)
{
    const int tid = threadIdx.x;
    if (tid < 128) b_pad[tid] = (tid < KC) ? b[tid] : -1e30f;
    if (tid < 64) {
        const int r16 = tid & 15, gg = tid >> 4;
        for (int t = 0; t < KT; ++t) {
            const int k = t * 16 + r16;
            for (int h = 0; h < 2; ++h) {
                short hi8[8], lo8[8];
                for (int j = 0; j < 8; ++j) {
                    const int c = h * 32 + gg * 8 + j;
                    float v = (k < KC) ? w[k * CD + c] : 0.f;
                    short hb = bfbits(v);
                    hi8[j] = hb;
                    lo8[j] = bfbits(v - bffloat(hb));
                }
                wfrag[((t * 2 + h) * 2 + 0) * 64 + tid] = *reinterpret_cast<uint4*>(hi8);
                wfrag[((t * 2 + h) * 2 + 1) * 64 + tid] = *reinterpret_cast<uint4*>(lo8);
            }
        }
    }
}

// Fused: staged x tile (LDS, read-once from HBM) + transposed logits MFMA +
// in-register softmax + register-direct agg MFMA (K=16 f16). 2 barriers/iter.
__global__ __launch_bounds__(256, 2) void k_fused(
    const float* __restrict__ x, const uint4* __restrict__ wfrag,
    const float* __restrict__ b_pad,
    float* __restrict__ agg_pT, float* __restrict__ asum_pT, int n0)
{
    __shared__ float xs[CD][65];                          // x tile [c][l] (16640 B)
    __shared__ __align__(16) uint4 wlds[KT * 2 * 2 * 64]; // 28672 B; reused as red buf
    __shared__ float asum_sm[4][KR];                      // 1792 B

    const int tid  = threadIdx.x;
    const int lane = tid & 63;
    const int wv   = tid >> 6;
    const int lloc = lane & 15;
    const int g    = lane >> 4;

    for (int i = tid; i < KT * 2 * 2 * 64; i += 256) wlds[i] = wfrag[i];

    const int nn = blockIdx.x >> 3;
    const int ls = blockIdx.x & 7;
    const int n  = n0 + nn;
    const float* xb = x + (size_t)n * CD * LD + ls * LCH;

    // bias: lane holds logits for k = lloc + 16t
    float bv7[KT];
#pragma unroll
    for (int t = 0; t < KT; ++t) bv7[t] = b_pad[t * 16 + lloc];

    f32x4 aagg[KT][4];
#pragma unroll
    for (int t = 0; t < KT; ++t)
#pragma unroll
        for (int ct = 0; ct < 4; ++ct) aagg[t][ct] = (f32x4){0.f, 0.f, 0.f, 0.f};
    float pasum[KT];
#pragma unroll
    for (int t = 0; t < KT; ++t) pasum[t] = 0.f;

    const bf16x8* wfp = reinterpret_cast<const bf16x8*>(wlds);
    const int lw = wv * 16 + lloc;     // lane's l for A-frag / softmax rows

    // prologue: prefetch iter 0's x tile (coalesced float4, full cache lines)
    float4 pv[4];
#pragma unroll
    for (int i = 0; i < 4; ++i) {
        int idx = tid + i * 256, c = idx >> 4, lq = idx & 15;
        pv[i] = *reinterpret_cast<const float4*>(xb + (size_t)c * LD + lq * 4);
    }

    __syncthreads();                   // wlds ready

    for (int it = 0; it < ITERS; ++it) {
        if (it) __syncthreads();       // S0: all xs readers done
        // stage x tile (fp32, exact)
#pragma unroll
        for (int i = 0; i < 4; ++i) {
            int idx = tid + i * 256, c = idx >> 4, lq = idx & 15;
            xs[c][lq * 4 + 0] = pv[i].x; xs[c][lq * 4 + 1] = pv[i].y;
            xs[c][lq * 4 + 2] = pv[i].z; xs[c][lq * 4 + 3] = pv[i].w;
        }
        __syncthreads();               // S1: xs ready

        // issue next tile's prefetch now; consumed at next S0 (hidden under compute)
        if (it + 1 < ITERS) {
#pragma unroll
            for (int i = 0; i < 4; ++i) {
                int idx = tid + i * 256, c = idx >> 4, lq = idx & 15;
                pv[i] = *reinterpret_cast<const float4*>(
                    xb + (it + 1) * 64 + (size_t)c * LD + lq * 4);
            }
        }

        // ---- A-frags (x hi/lo bf16) + sumsq over c (LDS column reads, 2-way = free) ----
        float ss = 0.f;
        bf16x8 xhi0, xlo0, xhi1, xlo1;
#pragma unroll
        for (int j = 0; j < 8; ++j) {
            float v0 = xs[g * 8 + j][lw];
            ss = fmaf(v0, v0, ss);
            short h0 = bfbits(v0);
            xhi0[j] = h0; xlo0[j] = bfbits(v0 - bffloat(h0));
            float v1 = xs[32 + g * 8 + j][lw];
            ss = fmaf(v1, v1, ss);
            short h1 = bfbits(v1);
            xhi1[j] = h1; xlo1[j] = bfbits(v1 - bffloat(h1));
        }
        ss += __shfl_xor(ss, 16);
        ss += __shfl_xor(ss, 32);
        const float rnl = 1.0f / fmaxf(sqrtf(ss), 1e-12f);
        float rnr[4];                  // rn for this lane's D rows l_local = g*4+r
#pragma unroll
        for (int r = 0; r < 4; ++r) rnr[r] = __shfl(rnl, g * 4 + r, 16);

        // ---- logits MFMA, TRANSPOSED: D[l][k] = mfma(A=x, B=W) ----
        f32x4 acc[KT];
#pragma unroll
        for (int t = 0; t < KT; ++t) acc[t] = (f32x4){0.f, 0.f, 0.f, 0.f};
#pragma unroll
        for (int t = 0; t < KT; ++t) {
            bf16x8 wh0 = wfp[((t * 2 + 0) * 2 + 0) * 64 + lane];
            bf16x8 wl0 = wfp[((t * 2 + 0) * 2 + 1) * 64 + lane];
            bf16x8 wh1 = wfp[((t * 2 + 1) * 2 + 0) * 64 + lane];
            bf16x8 wl1 = wfp[((t * 2 + 1) * 2 + 1) * 64 + lane];
            acc[t] = __builtin_amdgcn_mfma_f32_16x16x32_bf16(xhi0, wh0, acc[t], 0, 0, 0);
            acc[t] = __builtin_amdgcn_mfma_f32_16x16x32_bf16(xhi1, wh1, acc[t], 0, 0, 0);
            acc[t] = __builtin_amdgcn_mfma_f32_16x16x32_bf16(xlo0, wh0, acc[t], 0, 0, 0);
            acc[t] = __builtin_amdgcn_mfma_f32_16x16x32_bf16(xlo1, wh1, acc[t], 0, 0, 0);
            acc[t] = __builtin_amdgcn_mfma_f32_16x16x32_bf16(xhi0, wl0, acc[t], 0, 0, 0);
            acc[t] = __builtin_amdgcn_mfma_f32_16x16x32_bf16(xhi1, wl1, acc[t], 0, 0, 0);
        }

        // ---- softmax over k: lane holds logits[l=g*4+r][k=lloc+16t] ----
        float mr[4] = {-3.0e38f, -3.0e38f, -3.0e38f, -3.0e38f};
#pragma unroll
        for (int t = 0; t < KT; ++t) {
#pragma unroll
            for (int r = 0; r < 4; ++r) {
                acc[t][r] = fmaf(acc[t][r], rnr[r], bv7[t]);
                mr[r] = fmaxf(mr[r], acc[t][r]);
            }
        }
#pragma unroll
        for (int r = 0; r < 4; ++r) {
            mr[r] = fmaxf(mr[r], __shfl_xor(mr[r], 1));
            mr[r] = fmaxf(mr[r], __shfl_xor(mr[r], 2));
            mr[r] = fmaxf(mr[r], __shfl_xor(mr[r], 4));
            mr[r] = fmaxf(mr[r], __shfl_xor(mr[r], 8));
        }
        float sr[4] = {0.f, 0.f, 0.f, 0.f};
#pragma unroll
        for (int t = 0; t < KT; ++t) {
#pragma unroll
            for (int r = 0; r < 4; ++r) {
                float e = __expf(acc[t][r] - mr[r]);
                acc[t][r] = e;
                sr[r] += e;
            }
        }
#pragma unroll
        for (int r = 0; r < 4; ++r) {
            sr[r] += __shfl_xor(sr[r], 1);
            sr[r] += __shfl_xor(sr[r], 2);
            sr[r] += __shfl_xor(sr[r], 4);
            sr[r] += __shfl_xor(sr[r], 8);
            sr[r] = 1.0f / sr[r];
        }

        // ---- a (f32) -> f16 A-frags; asum partials from f32 a ----
        f16x4 pa[KT];
#pragma unroll
        for (int t = 0; t < KT; ++t) {
            float a0 = acc[t][0] * sr[0];
            float a1 = acc[t][1] * sr[1];
            float a2 = acc[t][2] * sr[2];
            float a3 = acc[t][3] * sr[3];
            pasum[t] += (a0 + a1) + (a2 + a3);
            pa[t][0] = (_Float16)a0; pa[t][1] = (_Float16)a1;
            pa[t][2] = (_Float16)a2; pa[t][3] = (_Float16)a3;
        }

        // ---- B-frags: x hi/lo f16 from xs rows (4x b32 each, <=4-way) ----
        f16x4 xh4[4], xl4[4];
        const int lcol = wv * 16 + g * 4;
#pragma unroll
        for (int ct = 0; ct < 4; ++ct) {
            const float* xr = &xs[ct * 16 + lloc][lcol];
#pragma unroll
            for (int j = 0; j < 4; ++j) {
                float v = xr[j];
                _Float16 h = (_Float16)v;
                xh4[ct][j] = h;
                xl4[ct][j] = (_Float16)(v - (float)h);
            }
        }

        // ---- agg MFMA (K=16, f16): aagg[t][ct] += a^T · x^T, straight from regs ----
#pragma unroll
        for (int t = 0; t < KT; ++t)
#pragma unroll
            for (int ct = 0; ct < 4; ++ct) {
                aagg[t][ct] = __builtin_amdgcn_mfma_f32_16x16x16f16(pa[t], xh4[ct], aagg[t][ct], 0, 0, 0);
                aagg[t][ct] = __builtin_amdgcn_mfma_f32_16x16x16f16(pa[t], xl4[ct], aagg[t][ct], 0, 0, 0);
            }
    }

    // ---- epilogue: asum reduce (g via shfl, waves via LDS) ----
#pragma unroll
    for (int t = 0; t < KT; ++t) {
        float v = pasum[t];
        v += __shfl_xor(v, 16);
        v += __shfl_xor(v, 32);
        if (g == 0) asum_sm[wv][t * 16 + lloc] = v;
    }
    __syncthreads();   // asum_sm ready; all waves done with xs/wlds

    const size_t nls = (size_t)nn * LSPLIT + ls;
    if (tid < KR)
        asum_pT[nls * KR + tid] = asum_sm[0][tid] + asum_sm[1][tid]
                                + asum_sm[2][tid] + asum_sm[3][tid];

    // ---- agg cross-wave reduce: 7 k-slices through LDS (reuse wlds) ----
    float* red = reinterpret_cast<float*>(wlds);   // [4][16][65] = 16640 B
#define RED(w, k, c) red[(((w) * 16 + (k)) * 65) + (c)]
    for (int t = 0; t < KT; ++t) {
        if (t) __syncthreads();        // prev slice fully consumed
        // D of agg: lane holds agg[k=16t+g*4+rg][c=16ct+lloc]
#pragma unroll
        for (int ct = 0; ct < 4; ++ct)
#pragma unroll
            for (int rg = 0; rg < 4; ++rg)
                RED(wv, g * 4 + rg, ct * 16 + lloc) = aagg[t][ct][rg];
        __syncthreads();
        const int kk = tid >> 4, c0 = (tid & 15) * 4;
        f32x4 v;
#pragma unroll
        for (int q = 0; q < 4; ++q)
            v[q] = RED(0, kk, c0 + q) + RED(1, kk, c0 + q)
                 + RED(2, kk, c0 + q) + RED(3, kk, c0 + q);
        *reinterpret_cast<f32x4*>(agg_pT + ((nls * 128 + t * 16 + kk) * 64 + c0)) = v;
    }
#undef RED
}

// Final: reduce partials ([nls][k128][c64] layout), subtract centroid*asum,
// intra-norm over C, global L2 norm.
__global__ __launch_bounds__(256, 1) void k_final(
    const float* __restrict__ agg_pT, const float* __restrict__ asum_pT,
    const float* __restrict__ cent, float* __restrict__ out, int n0)
{
    __shared__ float vbuf[KC][65];
    __shared__ float asum_s[KR];
    __shared__ float rn_s[KC];
    __shared__ float red[256];

    const int tid = threadIdx.x;
    const int nn  = blockIdx.x;
    const int n   = n0 + nn;
    const size_t nb8 = (size_t)nn * LSPLIT;

    if (tid < KR) {
        float s = 0.f;
#pragma unroll
        for (int ls = 0; ls < LSPLIT; ++ls)
            s += asum_pT[(nb8 + ls) * KR + tid];
        asum_s[tid] = s;
    }
    __syncthreads();

    for (int idx = tid; idx < 128 * 64; idx += 256) {
        int k = idx >> 6, c = idx & 63;
        if (k < KC) {
            float s = 0.f;
#pragma unroll
            for (int ls = 0; ls < LSPLIT; ++ls)
                s += agg_pT[((nb8 + ls) * 128 + k) * 64 + c];
            vbuf[k][c] = fmaf(-cent[k * CD + c], asum_s[k], s);
        }
    }
    __syncthreads();

    if (tid < KC) {
        float ssq = 0.f;
#pragma unroll 8
        for (int c = 0; c < CD; ++c) {
            float v = vbuf[tid][c];
            ssq = fmaf(v, v, ssq);
        }
        rn_s[tid] = 1.0f / fmaxf(sqrtf(ssq), 1e-12f);
    }
    __syncthreads();

    float gp = 0.f;
    for (int idx = tid; idx < KC * CD; idx += 256) {
        int k = idx >> 6, c = idx & 63;
        float v = vbuf[k][c] * rn_s[k];
        gp = fmaf(v, v, gp);
    }
    red[tid] = gp;
    __syncthreads();
    for (int off = 128; off > 0; off >>= 1) {
        if (tid < off) red[tid] += red[tid + off];
        __syncthreads();
    }
    const float gnorm = 1.0f / fmaxf(sqrtf(red[0]), 1e-12f);

    float* op = out + (size_t)n * (KC * CD);
    for (int idx = tid; idx < KC * CD; idx += 256) {
        int k = idx >> 6, c = idx & 63;
        op[idx] = vbuf[k][c] * rn_s[k] * gnorm;
    }
}

extern "C" void kernel_launch(void* const* d_in, const int* in_sizes, int n_in,
                              void* d_out, int out_size, void* d_ws, size_t ws_size,
                              hipStream_t stream)
{
    const float* x  = (const float*)d_in[0];
    const float* w  = (const float*)d_in[1];
    const float* b  = (const float*)d_in[2];
    const float* ct = (const float*)d_in[3];
    float* out = (float*)d_out;

    char* wsp = (char*)d_ws;
    uint4* wfrag = (uint4*)wsp;                 // 28672 B
    float* b_pad = (float*)(wsp + 28672);       // 512 B
    char* chunk  = wsp + 32768;

    const size_t agg_per_n  = (size_t)LSPLIT * 128 * 64 * 4; // 262144 B
    const size_t asum_per_n = (size_t)LSPLIT * KR * 4;       // 3584 B
    const size_t per_n = agg_per_n + asum_per_n;

    size_t avail = ws_size > 32768 ? ws_size - 32768 : 0;
    int nc = (int)(avail / per_n);
    if (nc < 1) nc = 1;
    if (nc > NB) nc = NB;

    float* agg_pT  = (float*)chunk;
    float* asum_pT = (float*)(chunk + agg_per_n * (size_t)nc);

    k_prep<<<1, 128, 0, stream>>>(w, b, wfrag, b_pad);
    for (int n0 = 0; n0 < NB; n0 += nc) {
        int cn = NB - n0; if (cn > nc) cn = nc;
        k_fused<<<cn * LSPLIT, 256, 0, stream>>>(x, wfrag, b_pad, agg_pT, asum_pT, n0);
        k_final<<<cn, 256, 0, stream>>>(agg_pT, asum_pT, ct, out, n0);
    }
}

// Round 10
// 89.993 us; speedup vs baseline: 2.6924x; 1.1317x over previous
//
#include <hip/hip_runtime.h>
#include <hip/hip_bf16.h>
#include <cstdint>

#define NB   128
#define CD   64
#define LD   4096
#define KC   100
#define KT   7            // 7 k-tiles of 16 -> 112 padded clusters
#define KR   (KT * 16)    // 112
#define LSPLIT 4
#define LCH  (LD / LSPLIT) // 1024 l's per block
#define ITERS (LCH / 64)   // 16 inner iters of 64 l

typedef __attribute__((ext_vector_type(8))) short bf16x8;
typedef __attribute__((ext_vector_type(4))) float f32x4;
typedef __attribute__((ext_vector_type(4))) _Float16 f16x4;

__device__ __forceinline__ short bfbits(float f) {
    __hip_bfloat16 h = __float2bfloat16(f);
    return *reinterpret_cast<short*>(&h);
}
__device__ __forceinline__ float bffloat(short s) {
    __hip_bfloat16 h = *reinterpret_cast<__hip_bfloat16*>(&s);
    return __bfloat162float(h);
}

// Precompute W fragments (bf16 hi/lo, zero-padded rows) + padded bias.
// wfrag[((t*2+h)*2+s)*64 + lane] = 8 bf16: W[t*16 + (lane&15)][h*32 + (lane>>4)*8 + 0..7]
__global__ void k_prep(const float* __restrict__ w, const float* __restrict__ b,
                       uint4* __restrict__ wfrag, float* __restrict__ b_pad)
{
    const int tid = threadIdx.x;
    if (tid < 128) b_pad[tid] = (tid < KC) ? b[tid] : -1e30f;
    if (tid < 64) {
        const int r16 = tid & 15, gg = tid >> 4;
        for (int t = 0; t < KT; ++t) {
            const int k = t * 16 + r16;
            for (int h = 0; h < 2; ++h) {
                short hi8[8], lo8[8];
                for (int j = 0; j < 8; ++j) {
                    const int c = h * 32 + gg * 8 + j;
                    float v = (k < KC) ? w[k * CD + c] : 0.f;
                    short hb = bfbits(v);
                    hi8[j] = hb;
                    lo8[j] = bfbits(v - bffloat(hb));
                }
                wfrag[((t * 2 + h) * 2 + 0) * 64 + tid] = *reinterpret_cast<uint4*>(hi8);
                wfrag[((t * 2 + h) * 2 + 1) * 64 + tid] = *reinterpret_cast<uint4*>(lo8);
            }
        }
    }
}

// Fused: double-buffered x tile (1 barrier/iter) + transposed logits MFMA +
// in-register softmax + register-direct agg MFMA (K=16 f16).
// Grid = nc*4 (512 at full chunk) = exactly 2 blocks/CU; LDS 63.7KB -> 2 blocks/CU.
__global__ __launch_bounds__(256, 2) void k_fused(
    const float* __restrict__ x, const uint4* __restrict__ wfrag,
    const float* __restrict__ b_pad,
    float* __restrict__ agg_pT, float* __restrict__ asum_pT, int n0)
{
    __shared__ float xs[2][CD][65];                       // x tiles [buf][c][l] (33280 B)
    __shared__ __align__(16) uint4 wlds[KT * 2 * 2 * 64]; // W frags (28672 B)
    __shared__ float asum_sm[4][KR];                      // 1792 B

    const int tid  = threadIdx.x;
    const int lane = tid & 63;
    const int wv   = tid >> 6;
    const int lloc = lane & 15;
    const int g    = lane >> 4;

    for (int i = tid; i < KT * 2 * 2 * 64; i += 256) wlds[i] = wfrag[i];

    const int nn = blockIdx.x >> 2;
    const int ls = blockIdx.x & 3;
    const int n  = n0 + nn;
    const float* xb = x + (size_t)n * CD * LD + ls * LCH;

    // bias: lane holds logits for k = lloc + 16t
    float bv7[KT];
#pragma unroll
    for (int t = 0; t < KT; ++t) bv7[t] = b_pad[t * 16 + lloc];

    f32x4 aagg[KT][4];
#pragma unroll
    for (int t = 0; t < KT; ++t)
#pragma unroll
        for (int ct = 0; ct < 4; ++ct) aagg[t][ct] = (f32x4){0.f, 0.f, 0.f, 0.f};
    float pasum[KT];
#pragma unroll
    for (int t = 0; t < KT; ++t) pasum[t] = 0.f;

    const bf16x8* wfp = reinterpret_cast<const bf16x8*>(wlds);
    const int lw = wv * 16 + lloc;     // lane's l for A-frag / softmax rows

    // prologue: load tile 0 and stage into xs[0]
    {
        float4 pv[4];
#pragma unroll
        for (int i = 0; i < 4; ++i) {
            int idx = tid + i * 256, c = idx >> 4, lq = idx & 15;
            pv[i] = *reinterpret_cast<const float4*>(xb + (size_t)c * LD + lq * 4);
        }
#pragma unroll
        for (int i = 0; i < 4; ++i) {
            int idx = tid + i * 256, c = idx >> 4, lq = idx & 15;
            xs[0][c][lq * 4 + 0] = pv[i].x; xs[0][c][lq * 4 + 1] = pv[i].y;
            xs[0][c][lq * 4 + 2] = pv[i].z; xs[0][c][lq * 4 + 3] = pv[i].w;
        }
    }
    __syncthreads();                   // wlds + xs[0] ready

    for (int it = 0; it < ITERS; ++it) {
        const int cur = it & 1;

        // issue next tile's global loads NOW (hidden under the whole compute phase)
        float4 pv[4];
        if (it + 1 < ITERS) {
#pragma unroll
            for (int i = 0; i < 4; ++i) {
                int idx = tid + i * 256, c = idx >> 4, lq = idx & 15;
                pv[i] = *reinterpret_cast<const float4*>(
                    xb + (it + 1) * 64 + (size_t)c * LD + lq * 4);
            }
        }

        // ---- A-frags (x hi/lo bf16) + sumsq over c (LDS column reads) ----
        float ss = 0.f;
        bf16x8 xhi0, xlo0, xhi1, xlo1;
#pragma unroll
        for (int j = 0; j < 8; ++j) {
            float v0 = xs[cur][g * 8 + j][lw];
            ss = fmaf(v0, v0, ss);
            short h0 = bfbits(v0);
            xhi0[j] = h0; xlo0[j] = bfbits(v0 - bffloat(h0));
            float v1 = xs[cur][32 + g * 8 + j][lw];
            ss = fmaf(v1, v1, ss);
            short h1 = bfbits(v1);
            xhi1[j] = h1; xlo1[j] = bfbits(v1 - bffloat(h1));
        }
        ss += __shfl_xor(ss, 16);
        ss += __shfl_xor(ss, 32);
        const float rnl = 1.0f / fmaxf(sqrtf(ss), 1e-12f);
        float rnr[4];                  // rn for this lane's D rows l_local = g*4+r
#pragma unroll
        for (int r = 0; r < 4; ++r) rnr[r] = __shfl(rnl, g * 4 + r, 16);

        // ---- logits MFMA, TRANSPOSED: D[l][k] = mfma(A=x, B=W) ----
        f32x4 acc[KT];
#pragma unroll
        for (int t = 0; t < KT; ++t) acc[t] = (f32x4){0.f, 0.f, 0.f, 0.f};
#pragma unroll
        for (int t = 0; t < KT; ++t) {
            bf16x8 wh0 = wfp[((t * 2 + 0) * 2 + 0) * 64 + lane];
            bf16x8 wl0 = wfp[((t * 2 + 0) * 2 + 1) * 64 + lane];
            bf16x8 wh1 = wfp[((t * 2 + 1) * 2 + 0) * 64 + lane];
            bf16x8 wl1 = wfp[((t * 2 + 1) * 2 + 1) * 64 + lane];
            acc[t] = __builtin_amdgcn_mfma_f32_16x16x32_bf16(xhi0, wh0, acc[t], 0, 0, 0);
            acc[t] = __builtin_amdgcn_mfma_f32_16x16x32_bf16(xhi1, wh1, acc[t], 0, 0, 0);
            acc[t] = __builtin_amdgcn_mfma_f32_16x16x32_bf16(xlo0, wh0, acc[t], 0, 0, 0);
            acc[t] = __builtin_amdgcn_mfma_f32_16x16x32_bf16(xlo1, wh1, acc[t], 0, 0, 0);
            acc[t] = __builtin_amdgcn_mfma_f32_16x16x32_bf16(xhi0, wl0, acc[t], 0, 0, 0);
            acc[t] = __builtin_amdgcn_mfma_f32_16x16x32_bf16(xhi1, wl1, acc[t], 0, 0, 0);
        }

        // ---- softmax over k: lane holds logits[l=g*4+r][k=lloc+16t] ----
        float mr[4] = {-3.0e38f, -3.0e38f, -3.0e38f, -3.0e38f};
#pragma unroll
        for (int t = 0; t < KT; ++t) {
#pragma unroll
            for (int r = 0; r < 4; ++r) {
                acc[t][r] = fmaf(acc[t][r], rnr[r], bv7[t]);
                mr[r] = fmaxf(mr[r], acc[t][r]);
            }
        }
#pragma unroll
        for (int r = 0; r < 4; ++r) {
            mr[r] = fmaxf(mr[r], __shfl_xor(mr[r], 1));
            mr[r] = fmaxf(mr[r], __shfl_xor(mr[r], 2));
            mr[r] = fmaxf(mr[r], __shfl_xor(mr[r], 4));
            mr[r] = fmaxf(mr[r], __shfl_xor(mr[r], 8));
        }
        float sr[4] = {0.f, 0.f, 0.f, 0.f};
#pragma unroll
        for (int t = 0; t < KT; ++t) {
#pragma unroll
            for (int r = 0; r < 4; ++r) {
                float e = __expf(acc[t][r] - mr[r]);
                acc[t][r] = e;
                sr[r] += e;
            }
        }
#pragma unroll
        for (int r = 0; r < 4; ++r) {
            sr[r] += __shfl_xor(sr[r], 1);
            sr[r] += __shfl_xor(sr[r], 2);
            sr[r] += __shfl_xor(sr[r], 4);
            sr[r] += __shfl_xor(sr[r], 8);
            sr[r] = 1.0f / sr[r];
        }

        // ---- a (f32) -> f16 A-frags; asum partials from f32 a ----
        f16x4 pa[KT];
#pragma unroll
        for (int t = 0; t < KT; ++t) {
            float a0 = acc[t][0] * sr[0];
            float a1 = acc[t][1] * sr[1];
            float a2 = acc[t][2] * sr[2];
            float a3 = acc[t][3] * sr[3];
            pasum[t] += (a0 + a1) + (a2 + a3);
            pa[t][0] = (_Float16)a0; pa[t][1] = (_Float16)a1;
            pa[t][2] = (_Float16)a2; pa[t][3] = (_Float16)a3;
        }

        // ---- B-frags: x hi/lo f16 from xs rows ----
        f16x4 xh4[4], xl4[4];
        const int lcol = wv * 16 + g * 4;
#pragma unroll
        for (int ct = 0; ct < 4; ++ct) {
            const float* xr = &xs[cur][ct * 16 + lloc][lcol];
#pragma unroll
            for (int j = 0; j < 4; ++j) {
                float v = xr[j];
                _Float16 h = (_Float16)v;
                xh4[ct][j] = h;
                xl4[ct][j] = (_Float16)(v - (float)h);
            }
        }

        // ---- agg MFMA (K=16, f16): straight from regs ----
#pragma unroll
        for (int t = 0; t < KT; ++t)
#pragma unroll
            for (int ct = 0; ct < 4; ++ct) {
                aagg[t][ct] = __builtin_amdgcn_mfma_f32_16x16x16f16(pa[t], xh4[ct], aagg[t][ct], 0, 0, 0);
                aagg[t][ct] = __builtin_amdgcn_mfma_f32_16x16x16f16(pa[t], xl4[ct], aagg[t][ct], 0, 0, 0);
            }

        // ---- stage next tile into the idle buffer, single barrier ----
        if (it + 1 < ITERS) {
#pragma unroll
            for (int i = 0; i < 4; ++i) {
                int idx = tid + i * 256, c = idx >> 4, lq = idx & 15;
                xs[cur ^ 1][c][lq * 4 + 0] = pv[i].x; xs[cur ^ 1][c][lq * 4 + 1] = pv[i].y;
                xs[cur ^ 1][c][lq * 4 + 2] = pv[i].z; xs[cur ^ 1][c][lq * 4 + 3] = pv[i].w;
            }
        }
        __syncthreads();
    }

    // ---- epilogue: asum reduce (g via shfl, waves via LDS) ----
#pragma unroll
    for (int t = 0; t < KT; ++t) {
        float v = pasum[t];
        v += __shfl_xor(v, 16);
        v += __shfl_xor(v, 32);
        if (g == 0) asum_sm[wv][t * 16 + lloc] = v;
    }
    __syncthreads();   // asum_sm ready; all waves past the loop

    const size_t nls = (size_t)nn * LSPLIT + ls;
    if (tid < KR)
        asum_pT[nls * KR + tid] = asum_sm[0][tid] + asum_sm[1][tid]
                                + asum_sm[2][tid] + asum_sm[3][tid];

    // ---- agg cross-wave reduce: 7 k-slices through LDS (reuse xs[0]: 16640 B exact) ----
    float* red = &xs[0][0][0];   // [4][16][65]
#define RED(w, k, c) red[(((w) * 16 + (k)) * 65) + (c)]
    for (int t = 0; t < KT; ++t) {
        if (t) __syncthreads();        // prev slice fully consumed
        // D of agg: lane holds agg[k=16t+g*4+rg][c=16ct+lloc]
#pragma unroll
        for (int ct = 0; ct < 4; ++ct)
#pragma unroll
            for (int rg = 0; rg < 4; ++rg)
                RED(wv, g * 4 + rg, ct * 16 + lloc) = aagg[t][ct][rg];
        __syncthreads();
        const int kk = tid >> 4, c0 = (tid & 15) * 4;
        f32x4 v;
#pragma unroll
        for (int q = 0; q < 4; ++q)
            v[q] = RED(0, kk, c0 + q) + RED(1, kk, c0 + q)
                 + RED(2, kk, c0 + q) + RED(3, kk, c0 + q);
        *reinterpret_cast<f32x4*>(agg_pT + ((nls * 128 + t * 16 + kk) * 64 + c0)) = v;
    }
#undef RED
}

// Final: reduce partials ([nls][k128][c64] layout), subtract centroid*asum,
// intra-norm over C, global L2 norm.
__global__ __launch_bounds__(256, 1) void k_final(
    const float* __restrict__ agg_pT, const float* __restrict__ asum_pT,
    const float* __restrict__ cent, float* __restrict__ out, int n0)
{
    __shared__ float vbuf[KC][65];
    __shared__ float asum_s[KR];
    __shared__ float rn_s[KC];
    __shared__ float red[256];

    const int tid = threadIdx.x;
    const int nn  = blockIdx.x;
    const int n   = n0 + nn;
    const size_t nb8 = (size_t)nn * LSPLIT;

    if (tid < KR) {
        float s = 0.f;
#pragma unroll
        for (int ls = 0; ls < LSPLIT; ++ls)
            s += asum_pT[(nb8 + ls) * KR + tid];
        asum_s[tid] = s;
    }
    __syncthreads();

    for (int idx = tid; idx < 128 * 64; idx += 256) {
        int k = idx >> 6, c = idx & 63;
        if (k < KC) {
            float s = 0.f;
#pragma unroll
            for (int ls = 0; ls < LSPLIT; ++ls)
                s += agg_pT[((nb8 + ls) * 128 + k) * 64 + c];
            vbuf[k][c] = fmaf(-cent[k * CD + c], asum_s[k], s);
        }
    }
    __syncthreads();

    if (tid < KC) {
        float ssq = 0.f;
#pragma unroll 8
        for (int c = 0; c < CD; ++c) {
            float v = vbuf[tid][c];
            ssq = fmaf(v, v, ssq);
        }
        rn_s[tid] = 1.0f / fmaxf(sqrtf(ssq), 1e-12f);
    }
    __syncthreads();

    float gp = 0.f;
    for (int idx = tid; idx < KC * CD; idx += 256) {
        int k = idx >> 6, c = idx & 63;
        float v = vbuf[k][c] * rn_s[k];
        gp = fmaf(v, v, gp);
    }
    red[tid] = gp;
    __syncthreads();
    for (int off = 128; off > 0; off >>= 1) {
        if (tid < off) red[tid] += red[tid + off];
        __syncthreads();
    }
    const float gnorm = 1.0f / fmaxf(sqrtf(red[0]), 1e-12f);

    float* op = out + (size_t)n * (KC * CD);
    for (int idx = tid; idx < KC * CD; idx += 256) {
        int k = idx >> 6, c = idx & 63;
        op[idx] = vbuf[k][c] * rn_s[k] * gnorm;
    }
}

extern "C" void kernel_launch(void* const* d_in, const int* in_sizes, int n_in,
                              void* d_out, int out_size, void* d_ws, size_t ws_size,
                              hipStream_t stream)
{
    const float* x  = (const float*)d_in[0];
    const float* w  = (const float*)d_in[1];
    const float* b  = (const float*)d_in[2];
    const float* ct = (const float*)d_in[3];
    float* out = (float*)d_out;

    char* wsp = (char*)d_ws;
    uint4* wfrag = (uint4*)wsp;                 // 28672 B
    float* b_pad = (float*)(wsp + 28672);       // 512 B
    char* chunk  = wsp + 32768;

    const size_t agg_per_n  = (size_t)LSPLIT * 128 * 64 * 4; // 131072 B
    const size_t asum_per_n = (size_t)LSPLIT * KR * 4;       // 1792 B
    const size_t per_n = agg_per_n + asum_per_n;

    size_t avail = ws_size > 32768 ? ws_size - 32768 : 0;
    int nc = (int)(avail / per_n);
    if (nc < 1) nc = 1;
    if (nc > NB) nc = NB;

    float* agg_pT  = (float*)chunk;
    float* asum_pT = (float*)(chunk + agg_per_n * (size_t)nc);

    k_prep<<<1, 128, 0, stream>>>(w, b, wfrag, b_pad);
    for (int n0 = 0; n0 < NB; n0 += nc) {
        int cn = NB - n0; if (cn > nc) cn = nc;
        k_fused<<<cn * LSPLIT, 256, 0, stream>>>(x, wfrag, b_pad, agg_pT, asum_pT, n0);
        k_final<<<cn, 256, 0, stream>>>(agg_pT, asum_pT, ct, out, n0);
    }
}